// Round 1
// baseline (122.133 us; speedup 1.0000x reference)
//
#include <hip/hip_runtime.h>
#include <math.h>

// Problem shapes (fixed by setup_inputs)
#define BB 16
#define NN 16384
#define DD 256     // == O
#define NS1 128    // blocks per batch, pass 1 (xsum)
#define NS3 128    // blocks per batch, pass 2 (scores + flash partials)

// ---------------- K1: partial column-sums of x ----------------
// grid (NS1, BB), block 256 (4 waves). Each block handles 128 rows.
// Wave w takes rows w, w+4, ...; lane l covers d = 4l..4l+3 (float4, 16B/lane).
__global__ __launch_bounds__(256) void k1_xsum_part(const float* __restrict__ x,
                                                    float* __restrict__ part) {
  const int b = blockIdx.y, blk = blockIdx.x;
  const int wave = threadIdx.x >> 6, lane = threadIdx.x & 63;
  const int rows = NN / NS1;  // 128
  const float* xp = x + ((size_t)b * NN + (size_t)blk * rows) * DD;
  float4 acc = make_float4(0.f, 0.f, 0.f, 0.f);
  for (int r = wave; r < rows; r += 4) {
    float4 v = *(const float4*)(xp + (size_t)r * DD + lane * 4);
    acc.x += v.x; acc.y += v.y; acc.z += v.z; acc.w += v.w;
  }
  __shared__ float sP[4][DD];
  *(float4*)&sP[wave][lane * 4] = acc;
  __syncthreads();
  const int t = threadIdx.x;
  part[((size_t)b * NS1 + blk) * DD + t] = sP[0][t] + sP[1][t] + sP[2][t] + sP[3][t];
}

// ---------------- K2: xsum reduce -> ksum -> v, c ----------------
// grid BB, block 256. thread t serves as index d and index o (D == O == 256).
__global__ __launch_bounds__(256) void k2_prep(const float* __restrict__ part,
                                               const float* __restrict__ Wq,
                                               const float* __restrict__ bq,
                                               const float* __restrict__ Wk,
                                               const float* __restrict__ bk,
                                               float* __restrict__ v,
                                               float* __restrict__ c) {
  const int b = blockIdx.x, t = threadIdx.x;
  __shared__ float xs[DD];
  __shared__ float ks[DD];
  __shared__ float red[256];

  float acc = 0.f;
  for (int blk = 0; blk < NS1; ++blk) acc += part[((size_t)b * NS1 + blk) * DD + t];
  xs[t] = acc;
  __syncthreads();

  // ksum[o] = Wk[o,:] . xsum + N*bk[o]
  float kacc = (float)NN * bk[t];
  const float* wkrow = Wk + (size_t)t * DD;
  for (int j = 0; j < DD; ++j) kacc += wkrow[j] * xs[j];
  ks[t] = kacc;
  __syncthreads();

  // v[d] = sum_o Wq[o,d] * ksum[o]   (coalesced over threads)
  float vacc = 0.f;
  for (int o = 0; o < DD; ++o) vacc += Wq[(size_t)o * DD + t] * ks[o];
  v[b * DD + t] = vacc;

  // c = bq . ksum
  red[t] = bq[t] * ks[t];
  __syncthreads();
  for (int s = 128; s > 0; s >>= 1) {
    if (t < s) red[t] += red[t + s];
    __syncthreads();
  }
  if (t == 0) c[b] = red[0];
}

// ---------------- K3: main pass — scores + flash partials ----------------
// grid (NS3, BB), block 256 (4 waves). Each wave owns 32 consecutive rows.
// Per row: s = (x_row . v + c) * scale; online softmax accumulating
// P[d] = sum exp(s - m)*x[d], Z = sum exp(s - m).
__global__ __launch_bounds__(256) void k3_main(const float* __restrict__ x,
                                               const float* __restrict__ v,
                                               const float* __restrict__ c,
                                               float* __restrict__ scores,
                                               float* __restrict__ pm,
                                               float* __restrict__ pz,
                                               float* __restrict__ pP) {
  const int b = blockIdx.y, blk = blockIdx.x;
  const int wave = threadIdx.x >> 6, lane = threadIdx.x & 63;
  const float scale = 0.0625f;  // 1/sqrt(256)

  const float4 vl = *(const float4*)(v + b * DD + lane * 4);
  const float cb = c[b];
  const int rows_per_block = NN / NS3;          // 128
  const int rows_per_wave = rows_per_block / 4; // 32
  const int n0 = blk * rows_per_block + wave * rows_per_wave;
  const float* xb = x + (size_t)b * NN * DD;

  float m = -INFINITY, Z = 0.f;
  float4 P = make_float4(0.f, 0.f, 0.f, 0.f);

  for (int i = 0; i < rows_per_wave; ++i) {
    const int n = n0 + i;
    float4 xr = *(const float4*)(xb + (size_t)n * DD + lane * 4);
    float dot = xr.x * vl.x + xr.y * vl.y + xr.z * vl.z + xr.w * vl.w;
#pragma unroll
    for (int off = 32; off >= 1; off >>= 1) dot += __shfl_xor(dot, off, 64);
    const float s = (dot + cb) * scale;
    if (lane == 0) scores[(size_t)b * NN + n] = s;

    const float mn = fmaxf(m, s);
    const float alpha = __expf(m - mn);  // m==-inf -> 0
    const float e = __expf(s - mn);
    Z = Z * alpha + e;
    P.x = P.x * alpha + e * xr.x;
    P.y = P.y * alpha + e * xr.y;
    P.z = P.z * alpha + e * xr.z;
    P.w = P.w * alpha + e * xr.w;
    m = mn;
  }

  // combine the 4 waves of this block
  __shared__ float sm[4], sz[4];
  __shared__ float sP[4][DD];
  *(float4*)&sP[wave][lane * 4] = P;
  if (lane == 0) { sm[wave] = m; sz[wave] = Z; }
  __syncthreads();

  const int t = threadIdx.x;
  const float M = fmaxf(fmaxf(sm[0], sm[1]), fmaxf(sm[2], sm[3]));
  const float e0 = __expf(sm[0] - M), e1 = __expf(sm[1] - M);
  const float e2 = __expf(sm[2] - M), e3 = __expf(sm[3] - M);
  const float Pd = sP[0][t] * e0 + sP[1][t] * e1 + sP[2][t] * e2 + sP[3][t] * e3;
  const size_t idx = (size_t)b * NS3 + blk;
  pP[idx * DD + t] = Pd;
  if (t == 0) {
    pm[idx] = M;
    pz[idx] = sz[0] * e0 + sz[1] * e1 + sz[2] * e2 + sz[3] * e3;
  }
}

// ---------------- K4: per-batch combine -> aggregated_feature, M, 1/Z ----------
__global__ __launch_bounds__(256) void k4_final(const float* __restrict__ pm,
                                                const float* __restrict__ pz,
                                                const float* __restrict__ pP,
                                                float* __restrict__ out_agg,
                                                float* __restrict__ Mb,
                                                float* __restrict__ rZb) {
  const int b = blockIdx.x, t = threadIdx.x;
  __shared__ float red[256];
  const size_t base = (size_t)b * NS3;

  // global max over block partial maxima
  red[t] = (t < NS3) ? pm[base + t] : -INFINITY;
  __syncthreads();
  for (int s = 128; s > 0; s >>= 1) {
    if (t < s) red[t] = fmaxf(red[t], red[t + s]);
    __syncthreads();
  }
  const float M = red[0];
  __syncthreads();

  // global Z
  red[t] = (t < NS3) ? pz[base + t] * __expf(pm[base + t] - M) : 0.f;
  __syncthreads();
  for (int s = 128; s > 0; s >>= 1) {
    if (t < s) red[t] += red[t + s];
    __syncthreads();
  }
  const float Z = red[0];
  const float rZ = 1.f / Z;

  // aggregated_feature[b, t]
  float acc = 0.f;
  for (int blk = 0; blk < NS3; ++blk)
    acc += pP[(base + blk) * DD + t] * __expf(pm[base + blk] - M);
  out_agg[b * DD + t] = acc * rZ;
  if (t == 0) { Mb[b] = M; rZb[b] = rZ; }
}

// ---------------- K5: average_customer_weights ----------------
__global__ __launch_bounds__(256) void k5_avgw(const float* __restrict__ scores,
                                               const float* __restrict__ Mb,
                                               const float* __restrict__ rZb,
                                               float* __restrict__ out_w) {
  const int n = blockIdx.x * blockDim.x + threadIdx.x;
  __shared__ float sM[BB], sR[BB];
  if (threadIdx.x < BB) { sM[threadIdx.x] = Mb[threadIdx.x]; sR[threadIdx.x] = rZb[threadIdx.x]; }
  __syncthreads();
  float acc = 0.f;
#pragma unroll
  for (int b = 0; b < BB; ++b)
    acc += __expf(scores[(size_t)b * NN + n] - sM[b]) * sR[b];
  out_w[n] = acc * (1.f / BB);
}

extern "C" void kernel_launch(void* const* d_in, const int* in_sizes, int n_in,
                              void* d_out, int out_size, void* d_ws, size_t ws_size,
                              hipStream_t stream) {
  const float* x  = (const float*)d_in[0];
  const float* Wq = (const float*)d_in[1];
  const float* bq = (const float*)d_in[2];
  const float* Wk = (const float*)d_in[3];
  const float* bk = (const float*)d_in[4];

  float* out  = (float*)d_out;
  float* agg  = out;             // [16, 256]
  float* avgw = out + BB * DD;   // [16384]

  float* ws = (float*)d_ws;
  float* part   = ws;  ws += (size_t)BB * NS1 * DD;  // 524288
  float* v      = ws;  ws += BB * DD;                // 4096
  float* c      = ws;  ws += BB;                     // 16
  float* scores = ws;  ws += (size_t)BB * NN;        // 262144
  float* pm     = ws;  ws += BB * NS3;               // 2048
  float* pz     = ws;  ws += BB * NS3;               // 2048
  float* pP     = ws;  ws += (size_t)BB * NS3 * DD;  // 524288
  float* Mb     = ws;  ws += BB;
  float* rZb    = ws;  ws += BB;

  k1_xsum_part<<<dim3(NS1, BB), 256, 0, stream>>>(x, part);
  k2_prep<<<BB, 256, 0, stream>>>(part, Wq, bq, Wk, bk, v, c);
  k3_main<<<dim3(NS3, BB), 256, 0, stream>>>(x, v, c, scores, pm, pz, pP);
  k4_final<<<BB, 256, 0, stream>>>(pm, pz, pP, agg, Mb, rZb);
  k5_avgw<<<NN / 256, 256, 0, stream>>>(scores, Mb, rZb, avgw);
}

// Round 2
// 119.511 us; speedup vs baseline: 1.0219x; 1.0219x over previous
//
#include <hip/hip_runtime.h>
#include <math.h>

// Problem shapes (fixed by setup_inputs)
#define BB 16
#define NN 16384
#define DD 256     // == O
#define NS1 128    // blocks per batch, pass 1 (xsum)
#define NS3 128    // blocks per batch, pass 2 (scores + flash partials)

// ---------------- K1: partial column-sums of x ----------------
// grid (NS1, BB), block 256 (4 waves). Each block handles 128 rows.
__global__ __launch_bounds__(256) void k1_xsum_part(const float* __restrict__ x,
                                                    float* __restrict__ part) {
  const int b = blockIdx.y, blk = blockIdx.x;
  const int wave = threadIdx.x >> 6, lane = threadIdx.x & 63;
  const int rows = NN / NS1;  // 128
  const float* xp = x + ((size_t)b * NN + (size_t)blk * rows) * DD;
  float4 acc = make_float4(0.f, 0.f, 0.f, 0.f);
  for (int r = wave; r < rows; r += 4) {
    float4 v = *(const float4*)(xp + (size_t)r * DD + lane * 4);
    acc.x += v.x; acc.y += v.y; acc.z += v.z; acc.w += v.w;
  }
  __shared__ float sP[4][DD];
  *(float4*)&sP[wave][lane * 4] = acc;
  __syncthreads();
  const int t = threadIdx.x;
  part[((size_t)b * NS1 + blk) * DD + t] = sP[0][t] + sP[1][t] + sP[2][t] + sP[3][t];
}

// ---------------- K2: xsum reduce -> ksum -> v, c ----------------
__global__ __launch_bounds__(256) void k2_prep(const float* __restrict__ part,
                                               const float* __restrict__ Wq,
                                               const float* __restrict__ bq,
                                               const float* __restrict__ Wk,
                                               const float* __restrict__ bk,
                                               float* __restrict__ v,
                                               float* __restrict__ c) {
  const int b = blockIdx.x, t = threadIdx.x;
  __shared__ float xs[DD];
  __shared__ float ks[DD];
  __shared__ float red[256];

  float acc = 0.f;
  for (int blk = 0; blk < NS1; ++blk) acc += part[((size_t)b * NS1 + blk) * DD + t];
  xs[t] = acc;
  __syncthreads();

  // ksum[o] = Wk[o,:] . xsum + N*bk[o]   (float4 row reads, xs broadcast from LDS)
  float kacc = (float)NN * bk[t];
  const float4* wkrow4 = (const float4*)(Wk + (size_t)t * DD);
#pragma unroll 4
  for (int j4 = 0; j4 < DD / 4; ++j4) {
    const float4 w = wkrow4[j4];
    kacc += w.x * xs[4 * j4] + w.y * xs[4 * j4 + 1] + w.z * xs[4 * j4 + 2] + w.w * xs[4 * j4 + 3];
  }
  ks[t] = kacc;
  __syncthreads();

  // v[d] = sum_o Wq[o,d] * ksum[o]   (coalesced over threads)
  float vacc = 0.f;
  for (int o = 0; o < DD; ++o) vacc += Wq[(size_t)o * DD + t] * ks[o];
  v[b * DD + t] = vacc;

  // c = bq . ksum
  red[t] = bq[t] * ks[t];
  __syncthreads();
  for (int s = 128; s > 0; s >>= 1) {
    if (t < s) red[t] += red[t + s];
    __syncthreads();
  }
  if (t == 0) c[b] = red[0];
}

// ---------------- K3: main pass — scores + flash partials ----------------
// REVERSED traversal: first-dispatched blocks touch the x that K1 touched LAST,
// maximizing Infinity-Cache (L3) hits (x is exactly 256 MiB = L3 capacity).
__global__ __launch_bounds__(256) void k3_main(const float* __restrict__ x,
                                               const float* __restrict__ v,
                                               const float* __restrict__ c,
                                               float* __restrict__ scores,
                                               float* __restrict__ pm,
                                               float* __restrict__ pz,
                                               float* __restrict__ pP) {
  const int b = BB - 1 - blockIdx.y;
  const int blk = NS3 - 1 - blockIdx.x;
  const int wave = threadIdx.x >> 6, lane = threadIdx.x & 63;
  const float scale = 0.0625f;  // 1/sqrt(256)

  const float4 vl = *(const float4*)(v + b * DD + lane * 4);
  const float cb = c[b];
  const int rows_per_block = NN / NS3;          // 128
  const int rows_per_wave = rows_per_block / 4; // 32
  const int n0 = blk * rows_per_block + wave * rows_per_wave;
  const float* xb = x + (size_t)b * NN * DD;

  float m = -INFINITY, Z = 0.f;
  float4 P = make_float4(0.f, 0.f, 0.f, 0.f);

  for (int i = 0; i < rows_per_wave; ++i) {
    const int n = n0 + i;
    float4 xr = *(const float4*)(xb + (size_t)n * DD + lane * 4);
    float dot = xr.x * vl.x + xr.y * vl.y + xr.z * vl.z + xr.w * vl.w;
#pragma unroll
    for (int off = 32; off >= 1; off >>= 1) dot += __shfl_xor(dot, off, 64);
    const float s = (dot + cb) * scale;
    if (lane == 0) scores[(size_t)b * NN + n] = s;

    const float mn = fmaxf(m, s);
    const float alpha = __expf(m - mn);  // m==-inf -> 0
    const float e = __expf(s - mn);
    Z = Z * alpha + e;
    P.x = P.x * alpha + e * xr.x;
    P.y = P.y * alpha + e * xr.y;
    P.z = P.z * alpha + e * xr.z;
    P.w = P.w * alpha + e * xr.w;
    m = mn;
  }

  // combine the 4 waves of this block
  __shared__ float sm[4], sz[4];
  __shared__ float sP[4][DD];
  *(float4*)&sP[wave][lane * 4] = P;
  if (lane == 0) { sm[wave] = m; sz[wave] = Z; }
  __syncthreads();

  const int t = threadIdx.x;
  const float M = fmaxf(fmaxf(sm[0], sm[1]), fmaxf(sm[2], sm[3]));
  const float e0 = __expf(sm[0] - M), e1 = __expf(sm[1] - M);
  const float e2 = __expf(sm[2] - M), e3 = __expf(sm[3] - M);
  const float Pd = sP[0][t] * e0 + sP[1][t] * e1 + sP[2][t] * e2 + sP[3][t] * e3;
  const size_t idx = (size_t)b * NS3 + blk;
  pP[idx * DD + t] = Pd;
  if (t == 0) {
    pm[idx] = M;
    pz[idx] = sz[0] * e0 + sz[1] * e1 + sz[2] * e2 + sz[3] * e3;
  }
}

// ---------------- K45: merged finalization ----------------
// Blocks 0..15 (role A): aggregated_feature[b].
// Blocks 16..79 (role B): average_customer_weights — each block redundantly
// recomputes all 16 (M_b, 1/Z_b) from pm/pz via 16-lane-group shuffle reduces.
__global__ __launch_bounds__(256) void k45_final(const float* __restrict__ pm,
                                                 const float* __restrict__ pz,
                                                 const float* __restrict__ pP,
                                                 const float* __restrict__ scores,
                                                 float* __restrict__ out_agg,
                                                 float* __restrict__ out_w) {
  const int t = threadIdx.x;
  if (blockIdx.x < BB) {
    // ---- role A ----
    const int b = blockIdx.x;
    __shared__ float red[256];
    const size_t base = (size_t)b * NS3;

    red[t] = (t < NS3) ? pm[base + t] : -INFINITY;
    __syncthreads();
    for (int s = 128; s > 0; s >>= 1) {
      if (t < s) red[t] = fmaxf(red[t], red[t + s]);
      __syncthreads();
    }
    const float M = red[0];
    __syncthreads();

    red[t] = (t < NS3) ? pz[base + t] * __expf(pm[base + t] - M) : 0.f;
    __syncthreads();
    for (int s = 128; s > 0; s >>= 1) {
      if (t < s) red[t] += red[t + s];
      __syncthreads();
    }
    const float rZ = 1.f / red[0];

    float acc = 0.f;
    for (int blk = 0; blk < NS3; ++blk)
      acc += pP[(base + blk) * DD + t] * __expf(pm[base + blk] - M);
    out_agg[b * DD + t] = acc * rZ;
  } else {
    // ---- role B ----
    const int wb = blockIdx.x - BB;
    __shared__ float sM[BB], sR[BB];
    const int b = t >> 4;       // 16 threads per batch
    const int i = t & 15;       // each covers 8 of the 128 partials
    const size_t base = (size_t)b * NS3 + i * 8;

    float mloc = -INFINITY;
#pragma unroll
    for (int k = 0; k < 8; ++k) mloc = fmaxf(mloc, pm[base + k]);
#pragma unroll
    for (int off = 8; off >= 1; off >>= 1) mloc = fmaxf(mloc, __shfl_xor(mloc, off, 64));
    const float M = mloc;

    float zloc = 0.f;
#pragma unroll
    for (int k = 0; k < 8; ++k) zloc += pz[base + k] * __expf(pm[base + k] - M);
#pragma unroll
    for (int off = 8; off >= 1; off >>= 1) zloc += __shfl_xor(zloc, off, 64);

    if (i == 0) { sM[b] = M; sR[b] = 1.f / zloc; }
    __syncthreads();

    const int n = wb * 256 + t;
    float acc = 0.f;
#pragma unroll
    for (int bb = 0; bb < BB; ++bb)
      acc += __expf(scores[(size_t)bb * NN + n] - sM[bb]) * sR[bb];
    out_w[n] = acc * (1.f / BB);
  }
}

extern "C" void kernel_launch(void* const* d_in, const int* in_sizes, int n_in,
                              void* d_out, int out_size, void* d_ws, size_t ws_size,
                              hipStream_t stream) {
  const float* x  = (const float*)d_in[0];
  const float* Wq = (const float*)d_in[1];
  const float* bq = (const float*)d_in[2];
  const float* Wk = (const float*)d_in[3];
  const float* bk = (const float*)d_in[4];

  float* out  = (float*)d_out;
  float* agg  = out;             // [16, 256]
  float* avgw = out + BB * DD;   // [16384]

  float* ws = (float*)d_ws;
  float* part   = ws;  ws += (size_t)BB * NS1 * DD;  // 524288
  float* v      = ws;  ws += BB * DD;                // 4096
  float* c      = ws;  ws += BB;                     // 16
  float* scores = ws;  ws += (size_t)BB * NN;        // 262144
  float* pm     = ws;  ws += BB * NS3;               // 2048
  float* pz     = ws;  ws += BB * NS3;               // 2048
  float* pP     = ws;  ws += (size_t)BB * NS3 * DD;  // 524288

  k1_xsum_part<<<dim3(NS1, BB), 256, 0, stream>>>(x, part);
  k2_prep<<<BB, 256, 0, stream>>>(part, Wq, bq, Wk, bk, v, c);
  k3_main<<<dim3(NS3, BB), 256, 0, stream>>>(x, v, c, scores, pm, pz, pP);
  k45_final<<<BB + NN / 256, 256, 0, stream>>>(pm, pz, pP, scores, agg, avgw);
}